// Round 9
// baseline (15472.998 us; speedup 1.0000x reference)
//
#include <hip/hip_runtime.h>
#include <hip/hip_bf16.h>
#include <stdint.h>

#define LSEQ 4096

typedef float f32x4 __attribute__((ext_vector_type(4)));
typedef int   i32x4 __attribute__((ext_vector_type(4)));
typedef int   i32x2 __attribute__((ext_vector_type(2)));

// ---------- helpers ----------
__device__ __forceinline__ float bflo(unsigned int u){ return __uint_as_float(u << 16); }
__device__ __forceinline__ float bfhi(unsigned int u){ return __uint_as_float(u & 0xFFFF0000u); }

__device__ __forceinline__ float wred(float v){
#pragma unroll
  for (int m = 1; m < 64; m <<= 1) v += __shfl_xor(v, m, 64);
  return v;
}

// pin a float4 into VGPRs component-wise
__device__ __forceinline__ void keep4(float4 &v){
  asm volatile("" : "+v"(v.x), "+v"(v.y), "+v"(v.z), "+v"(v.w));
}

// 8B LLC-coherent packet store {val, tag} — fire and forget
__device__ __forceinline__ void stg2_sc(float* p, i32x2 v){
  asm volatile("global_store_dwordx2 %0, %1, off sc0 sc1" :: "v"(p), "v"(v) : "memory");
}

// one probe of this thread's 4 packets (32B): both loads + waitcnt inside ONE
// asm block — no in-flight VMEM ever escapes an asm boundary (airtight
// pattern; R2's cross-block pipeline hung the GPU, R4's 2-deep in-block
// pipeline doubled probe traffic for no staggering benefit: +10% time).
__device__ __forceinline__ void ld_pkt2(const float* p, i32x4 &a, i32x4 &b){
  asm volatile("global_load_dwordx4 %0, %2, off sc0 sc1\n\t"
               "global_load_dwordx4 %1, %2, off offset:16 sc0 sc1\n\t"
               "s_waitcnt vmcnt(0)"
               : "=v"(a), "=v"(b) : "v"(p) : "memory");
}

// load 4 consecutive elements (bf16 or f32 source) as float4 (normal cached path)
__device__ __forceinline__ float4 load4g(const void* base, size_t off, int isb){
  if (isb){
    uint2 u = *(const uint2*)((const unsigned short*)base + off);
    return make_float4(bflo(u.x), bfhi(u.x), bflo(u.y), bfhi(u.y));
  }
  return *(const float4*)((const float*)base + off);
}
__device__ __forceinline__ float load1g(const void* base, int i, int isb){
  if (isb) return __uint_as_float(((unsigned int)((const unsigned short*)base)[i]) << 16);
  return ((const float*)base)[i];
}

// fmaf chain in fixed x,y,z,w order — must stay bit-identical across revisions.
// NOTE: macro params must NOT be named x/y/z/w (member tokens get substituted).
#define DOT4(acc, W_, V_) (acc) = fmaf((W_).w,(V_).w, fmaf((W_).z,(V_).z, fmaf((W_).y,(V_).y, fmaf((W_).x,(V_).x,(acc)))))

// ---------- dtype detector ----------
__global__ void detect_dtype(const unsigned int* __restrict__ w, int* __restrict__ dflag){
  int tid = threadIdx.x;
  int wild = 0;
  for (int i = tid; i < 4096; i += 256){
    unsigned int lo = w[i] & 0xFFFFu;
    int e = (lo >> 7) & 0xFF;
    if (e < 0x60 || e > 0x9A) wild++;
  }
  __shared__ int cnt;
  if (tid == 0) cnt = 0;
  __syncthreads();
  atomicAdd(&cnt, wild);
  __syncthreads();
  if (tid == 0) *dflag = (cnt * 2 < 4096) ? 1 : 0;
}

// ---------- per-token embedding max-norm scale ----------
__global__ void embed_scale(const int* __restrict__ tok, const void* __restrict__ E,
                            const int* __restrict__ dflag, float* __restrict__ scale){
  int isb = *dflag;
  int t = blockIdx.x * 4 + (threadIdx.x >> 6);
  int lane = threadIdx.x & 63;
  if (t >= LSEQ) return;
  int token = tok[t];
  float ss = 0.f;
#pragma unroll
  for (int j = 0; j < 2; ++j){
    float4 v = load4g(E, (size_t)token * 512 + 4 * lane + 256 * j, isb);
    ss += v.x * v.x + v.y * v.y + v.z * v.z + v.w * v.w;
  }
  ss = wred(ss);
  if (lane == 0){
    float nrm = sqrtf(ss);
    scale[t] = fminf(1.0f, 1.0f / fmaxf(nrm, 1e-7f));
  }
}

// ---------- persistent pipelined 2-layer GRU ----------
// 256 WGs x 512 thr (proven R3 shape; weights register/AGPR-pinned — R6
// showed scratch spill at 1024thr costs 2.2x, R7 showed L2-streaming WX
// costs +31%).
// Waves 0-3: layer0 rows 4b..4b+3; waves 4-7: layer1 rows.
// Exchange: per-ROW 8B packets {val, tag}, 2048 rows/slot, triple-buffered by
// s%3 (skew <= 1 superstep). Each wave's lane0 publishes its row immediately
// after the activation — no gather barrier.
// R9 changes vs R3 (sampling-phase only; protocol & numerics identical):
//  (1) L0's slack work (input projection + x-prefetch) runs INSIDE the poll
//      spin on the first miss — hidden under the LLC wait. CORRECTNESS
//      (R8 bug): the poll exit is made WAVE-UNIFORM via __all(hit), so
//      l0slack's wred shuffles always execute under a full exec mask.
//      Straggler WGs (first probe hits) degenerate to R3's serial slack.
//  (2) s_sleep(1) KEPT (R8 removed it; an unbounded coherent-load spin from
//      131k threads risks LLC congestion collapse per R4's measurement).
//  Slack writes a2n[] (double buffer), committed to a2c[] only after the
//  critical dot consumed the old value — bit-exact ordering preserved.
//  L1's slack reads the current step's hbuf so it stays post-publish.
// Loop runs s = 0..LSEQ+1 (4098 supersteps).
// Workspace (floats): [0..12287] arena: 3 slots x 2048 x {val,tag} | [12288]
// dtype | [12544..16639] scale.
__global__ __launch_bounds__(512, 1) void gru_persistent(
    const int* __restrict__ tok, const void* __restrict__ E,
    const void* __restrict__ Wih0, const void* __restrict__ Whh0,
    const void* __restrict__ bih0, const void* __restrict__ bhh0,
    const void* __restrict__ Wih1, const void* __restrict__ Whh1,
    const void* __restrict__ bih1, const void* __restrict__ bhh1,
    float* __restrict__ wsf, void* __restrict__ outv)
{
  __shared__ __align__(16) float hb[4096];   // double-buffered: h0|h1 per buffer
  float* hall = wsf;                          // 3 slots x 4096 floats
  const int isb = ((const int*)wsf)[12288];
  const float* scale = wsf + 12544;

  const int tid = threadIdx.x, bid = blockIdx.x;
  const int wave = tid >> 6, lane = tid & 63;
  const bool isL0 = wave < 4;
  const int hidx = bid * 4 + (wave & 3);
  const int grow = isL0 ? hidx : (1024 + hidx);   // global row index

  // ---- one-time weight load into registers, pinned ----
  // WH = recurrent weights (critical path), WX = input-side weights (slack)
  float4 WH[3][4], WX[3][4];
  float bI[3], bR[3];
#pragma unroll
  for (int g = 0; g < 3; ++g){
    size_t row = (size_t)(g * 1024 + hidx);
    if (isL0){
#pragma unroll
      for (int j = 0; j < 4; ++j) WH[g][j] = load4g(Whh0, row * 1024 + 4 * lane + 256 * j, isb);
#pragma unroll
      for (int j = 0; j < 2; ++j) WX[g][j] = load4g(Wih0, row * 512 + 4 * lane + 256 * j, isb);
      WX[g][2] = make_float4(0, 0, 0, 0); WX[g][3] = make_float4(0, 0, 0, 0);
      bI[g] = load1g(bih0, g * 1024 + hidx, isb);
      bR[g] = load1g(bhh0, g * 1024 + hidx, isb);
    } else {
#pragma unroll
      for (int j = 0; j < 4; ++j) WH[g][j] = load4g(Whh1, row * 1024 + 4 * lane + 256 * j, isb);
#pragma unroll
      for (int j = 0; j < 4; ++j) WX[g][j] = load4g(Wih1, row * 1024 + 4 * lane + 256 * j, isb);
      bI[g] = load1g(bih1, g * 1024 + hidx, isb);
      bR[g] = load1g(bhh1, g * 1024 + hidx, isb);
    }
  }
#pragma unroll
  for (int g = 0; g < 3; ++g){
#pragma unroll
    for (int j = 0; j < 4; ++j){
      keep4(WH[g][j]);
      if (!isL0 || j < 2) keep4(WX[g][j]);
    }
  }

  // ---- prologue: L0's a2 for step 0, and prefetch for step 1 ----
  float a2c[3] = {0.f, 0.f, 0.f};  // input-side pre-activations for CURRENT superstep
  float a2n[3] = {0.f, 0.f, 0.f};  // staging for NEXT superstep (committed post-critical)
  float4 xp0 = make_float4(0,0,0,0), xp1 = make_float4(0,0,0,0);
  float scp = 1.0f; int tkp = 0;
  if (isL0){
    int t0 = tok[0];
    float sc0_ = scale[0];
    float4 x0 = load4g(E, (size_t)t0 * 512 + 4 * lane, isb);
    float4 x1 = load4g(E, (size_t)t0 * 512 + 4 * lane + 256, isb);
    float ar = 0.f, az = 0.f, an = 0.f;
    DOT4(ar, WX[0][0], x0); DOT4(az, WX[1][0], x0); DOT4(an, WX[2][0], x0);
    DOT4(ar, WX[0][1], x1); DOT4(az, WX[1][1], x1); DOT4(an, WX[2][1], x1);
    ar = wred(ar); az = wred(az); an = wred(an);
    a2c[0] = sc0_ * ar + bI[0]; a2c[1] = sc0_ * az + bI[1]; a2c[2] = sc0_ * an + bI[2];
    int t1 = tok[1];
    scp = scale[1];
    xp0 = load4g(E, (size_t)t1 * 512 + 4 * lane, isb);
    xp1 = load4g(E, (size_t)t1 * 512 + 4 * lane + 256, isb);
    tkp = tok[2];
    keep4(xp0); keep4(xp1);
  }

  for (int s = 0; s <= LSEQ + 1; ++s){
    float* hbuf = hb + (s & 1) * 2048;

    // L0 slack: input-side projection for step s+1 (into a2n) + x prefetch.
    // Runs either inside the poll spin (full exec mask — loop is wave-
    // uniform) or post-publish. Same FMA/wred order as R3 — bit-exact.
    auto l0slack = [&](){
      if (s + 1 <= LSEQ - 1){
        float ar = 0.f, az = 0.f, an = 0.f;
        DOT4(ar, WX[0][0], xp0); DOT4(az, WX[1][0], xp0); DOT4(an, WX[2][0], xp0);
        DOT4(ar, WX[0][1], xp1); DOT4(az, WX[1][1], xp1); DOT4(an, WX[2][1], xp1);
        ar = wred(ar); az = wred(az); an = wred(an);
        a2n[0] = scp * ar + bI[0]; a2n[1] = scp * az + bI[1]; a2n[2] = scp * an + bI[2];
      }
      if (s + 2 <= LSEQ - 1){
        int tn = tkp;
        scp = scale[s + 2];
        xp0 = load4g(E, (size_t)tn * 512 + 4 * lane, isb);
        xp1 = load4g(E, (size_t)tn * 512 + 4 * lane + 256, isb);
        int t3 = s + 3; if (t3 > LSEQ - 1) t3 = LSEQ - 1;
        tkp = tok[t3];
        keep4(xp0); keep4(xp1);
      }
    };
    bool slack_done = false;

    // ---- poll thread's 4 packets for tag==s, stage to LDS ----
    // WAVE-UNIFORM exit (__all): l0slack's shuffles need full exec mask.
    {
      const float* pk = hall + ((s + 2) % 3) * 4096 + tid * 8;
      i32x4 a, b;
      for (;;){
        ld_pkt2(pk, a, b);
        bool hit = (a.y == s && a.w == s && b.y == s && b.w == s);
        if (__all(hit)) break;
        if (isL0 && !slack_done){ slack_done = true; l0slack(); }
        __builtin_amdgcn_s_sleep(1);
      }
      f32x4 v;
      v.x = __int_as_float(a.x); v.y = __int_as_float(a.z);
      v.z = __int_as_float(b.x); v.w = __int_as_float(b.z);
      *(((f32x4*)hbuf) + tid) = v;   // rows 4*tid .. 4*tid+3
    }
    __syncthreads();   // the only barrier per superstep

    // ---- critical path: recurrent dot + activation ----
    const bool active = isL0 ? (s <= LSEQ - 1) : (s >= 2);
    float hprev = isL0 ? hbuf[hidx] : hbuf[1024 + hidx];
    float hnew = hprev;
    if (active){
      const float4* HP = (const float4*)(isL0 ? hbuf : (hbuf + 1024));
      float b1 = 0.f, b2 = 0.f, b3 = 0.f;
#pragma unroll
      for (int j = 0; j < 4; ++j){
        float4 h = HP[lane + 64 * j];
        DOT4(b1, WH[0][j], h); DOT4(b2, WH[1][j], h); DOT4(b3, WH[2][j], h);
      }
      b1 = wred(b1); b2 = wred(b2); b3 = wred(b3);
      float ipr = a2c[0], ipz = a2c[1], ipn = a2c[2];
      float rpr = b1 + bR[0], rpz = b2 + bR[1], rpn = b3 + bR[2];
      float r = 1.0f / (1.0f + expf(-(ipr + rpr)));
      float z = 1.0f / (1.0f + expf(-(ipz + rpz)));
      float n = tanhf(ipn + r * rpn);
      hnew = (1.0f - z) * n + z * hprev;
    }

    // ---- immediate per-wave publish (8B packet) + final outputs ----
    if (lane == 0){
      if (s <= LSEQ){
        float* pp = hall + (s % 3) * 4096 + grow * 2;
        i32x2 P; P.x = __float_as_int(hnew); P.y = s + 1;
        stg2_sc(pp, P);
      }
      if (isb){
        __hip_bfloat16* ob = (__hip_bfloat16*)outv;
        if (isL0 && s == LSEQ - 1) ob[1024 + hidx] = __float2bfloat16(hnew);        // hidden[0]
        if (!isL0 && s == LSEQ + 1){ ob[hidx] = __float2bfloat16(hnew);             // out
                                     ob[2048 + hidx] = __float2bfloat16(hnew); }    // hidden[1]
      } else {
        float* of = (float*)outv;
        if (isL0 && s == LSEQ - 1) of[1024 + hidx] = hnew;
        if (!isL0 && s == LSEQ + 1){ of[hidx] = hnew; of[2048 + hidx] = hnew; }
      }
    }

    // ---- slack completion + commit ----
    if (isL0){
      if (!slack_done) l0slack();
      if (s + 1 <= LSEQ - 1){ a2c[0] = a2n[0]; a2c[1] = a2n[1]; a2c[2] = a2n[2]; }
    } else {
      if (s >= 1 && s <= LSEQ){
        // a2 for h1(s-1): Wih1 · h0(s-1), h0(s-1) is in this superstep's hbuf
        float ar = 0.f, az = 0.f, an = 0.f;
#pragma unroll
        for (int j = 0; j < 4; ++j){
          float4 x = ((const float4*)hbuf)[lane + 64 * j];
          DOT4(ar, WX[0][j], x); DOT4(az, WX[1][j], x); DOT4(an, WX[2][j], x);
        }
        ar = wred(ar); az = wred(az); an = wred(an);
        a2c[0] = ar + bI[0]; a2c[1] = az + bI[1]; a2c[2] = an + bI[2];
      }
    }
  }
}

extern "C" void kernel_launch(void* const* d_in, const int* in_sizes, int n_in,
                              void* d_out, int out_size, void* d_ws, size_t ws_size,
                              hipStream_t stream) {
  const int*  tokens = (const int*)d_in[0];
  const void* E    = d_in[1];
  const void* Wih0 = d_in[2];
  const void* Whh0 = d_in[3];
  const void* bih0 = d_in[4];
  const void* bhh0 = d_in[5];
  const void* Wih1 = d_in[6];
  const void* Whh1 = d_in[7];
  const void* bih1 = d_in[8];
  const void* bhh1 = d_in[9];
  float* wsf = (float*)d_ws;

  // zero the 3-slot packet arena (tags must start at 0)
  (void)hipMemsetAsync(d_ws, 0, 49152, stream);
  hipLaunchKernelGGL(detect_dtype, dim3(1), dim3(256), 0, stream,
                     (const unsigned int*)E, ((int*)d_ws) + 12288);
  hipLaunchKernelGGL(embed_scale, dim3(1024), dim3(256), 0, stream,
                     tokens, E, ((const int*)d_ws) + 12288, wsf + 12544);

  void* args[] = { (void*)&tokens, (void*)&E, (void*)&Wih0, (void*)&Whh0,
                   (void*)&bih0, (void*)&bhh0, (void*)&Wih1, (void*)&Whh1,
                   (void*)&bih1, (void*)&bhh1, (void*)&wsf, (void*)&d_out };
  (void)hipLaunchCooperativeKernel((void*)gru_persistent, dim3(256), dim3(512),
                                   args, 0, stream);
}

// Round 10
// 8396.754 us; speedup vs baseline: 1.8427x; 1.8427x over previous
//
#include <hip/hip_runtime.h>
#include <hip/hip_bf16.h>
#include <stdint.h>

#define LSEQ 4096

typedef float f32x4 __attribute__((ext_vector_type(4)));
typedef int   i32x4 __attribute__((ext_vector_type(4)));
typedef int   i32x2 __attribute__((ext_vector_type(2)));

// ---------- helpers ----------
__device__ __forceinline__ float bflo(unsigned int u){ return __uint_as_float(u << 16); }
__device__ __forceinline__ float bfhi(unsigned int u){ return __uint_as_float(u & 0xFFFF0000u); }

__device__ __forceinline__ float wred(float v){
#pragma unroll
  for (int m = 1; m < 64; m <<= 1) v += __shfl_xor(v, m, 64);
  return v;
}

// pin a float4 into VGPRs component-wise
__device__ __forceinline__ void keep4(float4 &v){
  asm volatile("" : "+v"(v.x), "+v"(v.y), "+v"(v.z), "+v"(v.w));
}

// 8B LLC-coherent packet store {val, tag} — fire and forget
__device__ __forceinline__ void stg2_sc(float* p, i32x2 v){
  asm volatile("global_store_dwordx2 %0, %1, off sc0 sc1" :: "v"(p), "v"(v) : "memory");
}

// one probe of this thread's 4 packets (32B): both loads + waitcnt inside ONE
// asm block — no in-flight VMEM ever escapes an asm boundary (the airtight
// pattern; R2's cross-block pipeline hung the GPU, R4's 2-deep in-block
// pipeline doubled probe traffic for no staggering benefit: +10%, R9's
// slack-in-poll put VALU work on the detection path: +84%).
__device__ __forceinline__ void ld_pkt2(const float* p, i32x4 &a, i32x4 &b){
  asm volatile("global_load_dwordx4 %0, %2, off sc0 sc1\n\t"
               "global_load_dwordx4 %1, %2, off offset:16 sc0 sc1\n\t"
               "s_waitcnt vmcnt(0)"
               : "=v"(a), "=v"(b) : "v"(p) : "memory");
}

// load 4 consecutive elements (bf16 or f32 source) as float4 (normal cached path)
__device__ __forceinline__ float4 load4g(const void* base, size_t off, int isb){
  if (isb){
    uint2 u = *(const uint2*)((const unsigned short*)base + off);
    return make_float4(bflo(u.x), bfhi(u.x), bflo(u.y), bfhi(u.y));
  }
  return *(const float4*)((const float*)base + off);
}
__device__ __forceinline__ float load1g(const void* base, int i, int isb){
  if (isb) return __uint_as_float(((unsigned int)((const unsigned short*)base)[i]) << 16);
  return ((const float*)base)[i];
}

// fmaf chain in fixed x,y,z,w order — must stay bit-identical across revisions.
// NOTE: macro params must NOT be named x/y/z/w (member tokens get substituted).
#define DOT4(acc, W_, V_) (acc) = fmaf((W_).w,(V_).w, fmaf((W_).z,(V_).z, fmaf((W_).y,(V_).y, fmaf((W_).x,(V_).x,(acc)))))

// ---------- dtype detector ----------
__global__ void detect_dtype(const unsigned int* __restrict__ w, int* __restrict__ dflag){
  int tid = threadIdx.x;
  int wild = 0;
  for (int i = tid; i < 4096; i += 256){
    unsigned int lo = w[i] & 0xFFFFu;
    int e = (lo >> 7) & 0xFF;
    if (e < 0x60 || e > 0x9A) wild++;
  }
  __shared__ int cnt;
  if (tid == 0) cnt = 0;
  __syncthreads();
  atomicAdd(&cnt, wild);
  __syncthreads();
  if (tid == 0) *dflag = (cnt * 2 < 4096) ? 1 : 0;
}

// ---------- per-token embedding max-norm scale ----------
__global__ void embed_scale(const int* __restrict__ tok, const void* __restrict__ E,
                            const int* __restrict__ dflag, float* __restrict__ scale){
  int isb = *dflag;
  int t = blockIdx.x * 4 + (threadIdx.x >> 6);
  int lane = threadIdx.x & 63;
  if (t >= LSEQ) return;
  int token = tok[t];
  float ss = 0.f;
#pragma unroll
  for (int j = 0; j < 2; ++j){
    float4 v = load4g(E, (size_t)token * 512 + 4 * lane + 256 * j, isb);
    ss += v.x * v.x + v.y * v.y + v.z * v.z + v.w * v.w;
  }
  ss = wred(ss);
  if (lane == 0){
    float nrm = sqrtf(ss);
    scale[t] = fminf(1.0f, 1.0f / fmaxf(nrm, 1e-7f));
  }
}

// ---------- persistent pipelined 2-layer GRU ----------
// CHAMPION STRUCTURE (R3 = 8410us). Measured local optimum:
//   R4  (2-deep poll, 2x probe traffic)        +10%  — LLC exchange is congestion-sensitive
//   R6  (1024thr; WH spilled to scratch)       +116% — recurrent weights MUST stay reg/AGPR
//   R7  (WX streamed from L2 in slack)         +31%  — L2 stream lands on the step cycle
//   R9  (slack moved into the poll spin)       +84%  — slack was ALREADY hidden post-publish;
//                                                      in-spin it gates detection device-wide
// Step budget ~2.05us: ~1.8us protocol latency (publish -> LLC visibility ->
// detect; max over the 1024 same-layer packets — irreducible while each wave
// consumes its full layer under SIMT lockstep) + ~0.25us compute.
// 256 WGs x 512 thr. Waves 0-3: layer0 rows 4b..4b+3; waves 4-7: layer1 rows.
// Exchange: per-ROW 8B packets {val, tag}, 2048 rows/slot, triple-buffered by
// s%3 (skew <= 1 superstep). Each wave's lane0 publishes its row immediately
// after the activation — no gather barrier. Input-side projections (Wih·x)
// are computed in the slack phase one superstep ahead (post-publish, hidden
// in the packet flight window); only the recurrent dot + 3 wreds + activation
// are on the critical path. L1 runs with 2-superstep skew.
// Loop runs s = 0..LSEQ+1 (4098 supersteps).
// Workspace (floats): [0..12287] arena: 3 slots x 2048 x {val,tag} | [12288]
// dtype | [12544..16639] scale.
__global__ __launch_bounds__(512, 1) void gru_persistent(
    const int* __restrict__ tok, const void* __restrict__ E,
    const void* __restrict__ Wih0, const void* __restrict__ Whh0,
    const void* __restrict__ bih0, const void* __restrict__ bhh0,
    const void* __restrict__ Wih1, const void* __restrict__ Whh1,
    const void* __restrict__ bih1, const void* __restrict__ bhh1,
    float* __restrict__ wsf, void* __restrict__ outv)
{
  __shared__ __align__(16) float hb[4096];   // double-buffered: h0|h1 per buffer
  float* hall = wsf;                          // 3 slots x 4096 floats
  const int isb = ((const int*)wsf)[12288];
  const float* scale = wsf + 12544;

  const int tid = threadIdx.x, bid = blockIdx.x;
  const int wave = tid >> 6, lane = tid & 63;
  const bool isL0 = wave < 4;
  const int hidx = bid * 4 + (wave & 3);
  const int grow = isL0 ? hidx : (1024 + hidx);   // global row index

  // ---- one-time weight load into registers, pinned ----
  // WH = recurrent weights (critical path), WX = input-side weights (slack)
  float4 WH[3][4], WX[3][4];
  float bI[3], bR[3];
#pragma unroll
  for (int g = 0; g < 3; ++g){
    size_t row = (size_t)(g * 1024 + hidx);
    if (isL0){
#pragma unroll
      for (int j = 0; j < 4; ++j) WH[g][j] = load4g(Whh0, row * 1024 + 4 * lane + 256 * j, isb);
#pragma unroll
      for (int j = 0; j < 2; ++j) WX[g][j] = load4g(Wih0, row * 512 + 4 * lane + 256 * j, isb);
      WX[g][2] = make_float4(0, 0, 0, 0); WX[g][3] = make_float4(0, 0, 0, 0);
      bI[g] = load1g(bih0, g * 1024 + hidx, isb);
      bR[g] = load1g(bhh0, g * 1024 + hidx, isb);
    } else {
#pragma unroll
      for (int j = 0; j < 4; ++j) WH[g][j] = load4g(Whh1, row * 1024 + 4 * lane + 256 * j, isb);
#pragma unroll
      for (int j = 0; j < 4; ++j) WX[g][j] = load4g(Wih1, row * 1024 + 4 * lane + 256 * j, isb);
      bI[g] = load1g(bih1, g * 1024 + hidx, isb);
      bR[g] = load1g(bhh1, g * 1024 + hidx, isb);
    }
  }
#pragma unroll
  for (int g = 0; g < 3; ++g){
#pragma unroll
    for (int j = 0; j < 4; ++j){
      keep4(WH[g][j]);
      if (!isL0 || j < 2) keep4(WX[g][j]);
    }
  }

  // ---- prologue: L0's a2 for step 0, and prefetch for step 1 ----
  float a2c[3] = {0.f, 0.f, 0.f};  // input-side pre-activations for CURRENT superstep
  float4 xp0 = make_float4(0,0,0,0), xp1 = make_float4(0,0,0,0);
  float scp = 1.0f; int tkp = 0;
  if (isL0){
    int t0 = tok[0];
    float sc0_ = scale[0];
    float4 x0 = load4g(E, (size_t)t0 * 512 + 4 * lane, isb);
    float4 x1 = load4g(E, (size_t)t0 * 512 + 4 * lane + 256, isb);
    float ar = 0.f, az = 0.f, an = 0.f;
    DOT4(ar, WX[0][0], x0); DOT4(az, WX[1][0], x0); DOT4(an, WX[2][0], x0);
    DOT4(ar, WX[0][1], x1); DOT4(az, WX[1][1], x1); DOT4(an, WX[2][1], x1);
    ar = wred(ar); az = wred(az); an = wred(an);
    a2c[0] = sc0_ * ar + bI[0]; a2c[1] = sc0_ * az + bI[1]; a2c[2] = sc0_ * an + bI[2];
    int t1 = tok[1];
    scp = scale[1];
    xp0 = load4g(E, (size_t)t1 * 512 + 4 * lane, isb);
    xp1 = load4g(E, (size_t)t1 * 512 + 4 * lane + 256, isb);
    tkp = tok[2];
    keep4(xp0); keep4(xp1);
  }

  for (int s = 0; s <= LSEQ + 1; ++s){
    float* hbuf = hb + (s & 1) * 2048;

    // ---- poll thread's 4 packets for tag==s, stage to LDS ----
    {
      const float* pk = hall + ((s + 2) % 3) * 4096 + tid * 8;
      i32x4 a, b;
      for (;;){
        ld_pkt2(pk, a, b);
        if (a.y == s && a.w == s && b.y == s && b.w == s) break;
        __builtin_amdgcn_s_sleep(1);
      }
      f32x4 v;
      v.x = __int_as_float(a.x); v.y = __int_as_float(a.z);
      v.z = __int_as_float(b.x); v.w = __int_as_float(b.z);
      *(((f32x4*)hbuf) + tid) = v;   // rows 4*tid .. 4*tid+3
    }
    __syncthreads();   // the only barrier per superstep

    // ---- critical path: recurrent dot + activation ----
    const bool active = isL0 ? (s <= LSEQ - 1) : (s >= 2);
    float hprev = isL0 ? hbuf[hidx] : hbuf[1024 + hidx];
    float hnew = hprev;
    if (active){
      const float4* HP = (const float4*)(isL0 ? hbuf : (hbuf + 1024));
      float b1 = 0.f, b2 = 0.f, b3 = 0.f;
#pragma unroll
      for (int j = 0; j < 4; ++j){
        float4 h = HP[lane + 64 * j];
        DOT4(b1, WH[0][j], h); DOT4(b2, WH[1][j], h); DOT4(b3, WH[2][j], h);
      }
      b1 = wred(b1); b2 = wred(b2); b3 = wred(b3);
      float ipr = a2c[0], ipz = a2c[1], ipn = a2c[2];
      float rpr = b1 + bR[0], rpz = b2 + bR[1], rpn = b3 + bR[2];
      float r = 1.0f / (1.0f + expf(-(ipr + rpr)));
      float z = 1.0f / (1.0f + expf(-(ipz + rpz)));
      float n = tanhf(ipn + r * rpn);
      hnew = (1.0f - z) * n + z * hprev;
    }

    // ---- immediate per-wave publish (8B packet) + final outputs ----
    if (lane == 0){
      if (s <= LSEQ){
        float* pp = hall + (s % 3) * 4096 + grow * 2;
        i32x2 P; P.x = __float_as_int(hnew); P.y = s + 1;
        stg2_sc(pp, P);
      }
      if (isb){
        __hip_bfloat16* ob = (__hip_bfloat16*)outv;
        if (isL0 && s == LSEQ - 1) ob[1024 + hidx] = __float2bfloat16(hnew);        // hidden[0]
        if (!isL0 && s == LSEQ + 1){ ob[hidx] = __float2bfloat16(hnew);             // out
                                     ob[2048 + hidx] = __float2bfloat16(hnew); }    // hidden[1]
      } else {
        float* of = (float*)outv;
        if (isL0 && s == LSEQ - 1) of[1024 + hidx] = hnew;
        if (!isL0 && s == LSEQ + 1){ of[hidx] = hnew; of[2048 + hidx] = hnew; }
      }
    }

    // ---- slack phase: input-side projections for the NEXT superstep ----
    // (post-publish: hidden in the packet flight window — R9 proved moving
    // this earlier puts it on the detection critical path)
    if (isL0){
      if (s + 1 <= LSEQ - 1){
        float ar = 0.f, az = 0.f, an = 0.f;
        DOT4(ar, WX[0][0], xp0); DOT4(az, WX[1][0], xp0); DOT4(an, WX[2][0], xp0);
        DOT4(ar, WX[0][1], xp1); DOT4(az, WX[1][1], xp1); DOT4(an, WX[2][1], xp1);
        ar = wred(ar); az = wred(az); an = wred(an);
        a2c[0] = scp * ar + bI[0]; a2c[1] = scp * az + bI[1]; a2c[2] = scp * an + bI[2];
      }
      if (s + 2 <= LSEQ - 1){
        int tn = tkp;
        scp = scale[s + 2];
        xp0 = load4g(E, (size_t)tn * 512 + 4 * lane, isb);
        xp1 = load4g(E, (size_t)tn * 512 + 4 * lane + 256, isb);
        int t3 = s + 3; if (t3 > LSEQ - 1) t3 = LSEQ - 1;
        tkp = tok[t3];
        keep4(xp0); keep4(xp1);
      }
    } else {
      if (s >= 1 && s <= LSEQ){
        // a2 for h1(s-1): Wih1 · h0(s-1), h0(s-1) is in this superstep's hbuf
        float ar = 0.f, az = 0.f, an = 0.f;
#pragma unroll
        for (int j = 0; j < 4; ++j){
          float4 x = ((const float4*)hbuf)[lane + 64 * j];
          DOT4(ar, WX[0][j], x); DOT4(az, WX[1][j], x); DOT4(an, WX[2][j], x);
        }
        ar = wred(ar); az = wred(az); an = wred(an);
        a2c[0] = ar + bI[0]; a2c[1] = az + bI[1]; a2c[2] = an + bI[2];
      }
    }
  }
}

extern "C" void kernel_launch(void* const* d_in, const int* in_sizes, int n_in,
                              void* d_out, int out_size, void* d_ws, size_t ws_size,
                              hipStream_t stream) {
  const int*  tokens = (const int*)d_in[0];
  const void* E    = d_in[1];
  const void* Wih0 = d_in[2];
  const void* Whh0 = d_in[3];
  const void* bih0 = d_in[4];
  const void* bhh0 = d_in[5];
  const void* Wih1 = d_in[6];
  const void* Whh1 = d_in[7];
  const void* bih1 = d_in[8];
  const void* bhh1 = d_in[9];
  float* wsf = (float*)d_ws;

  // zero the 3-slot packet arena (tags must start at 0)
  (void)hipMemsetAsync(d_ws, 0, 49152, stream);
  hipLaunchKernelGGL(detect_dtype, dim3(1), dim3(256), 0, stream,
                     (const unsigned int*)E, ((int*)d_ws) + 12288);
  hipLaunchKernelGGL(embed_scale, dim3(1024), dim3(256), 0, stream,
                     tokens, E, ((const int*)d_ws) + 12288, wsf + 12544);

  void* args[] = { (void*)&tokens, (void*)&E, (void*)&Wih0, (void*)&Whh0,
                   (void*)&bih0, (void*)&bhh0, (void*)&Wih1, (void*)&Whh1,
                   (void*)&bih1, (void*)&bhh1, (void*)&wsf, (void*)&d_out };
  (void)hipLaunchCooperativeKernel((void*)gru_persistent, dim3(256), dim3(512),
                                   args, 0, stream);
}